// Round 12
// baseline (220.092 us; speedup 1.0000x reference)
//
#include <hip/hip_runtime.h>
#include <hip/hip_bf16.h>

// Problem constants
#define NPAT 4096   // patches
#define EDIM 64     // embedding per head
#define NH   8      // heads
#define HE   512    // H*E
#define OUTD 64     // CIN*P^3

typedef short bf16x8 __attribute__((ext_vector_type(8)));
typedef float f32x4  __attribute__((ext_vector_type(4)));
typedef unsigned short u16x4 __attribute__((ext_vector_type(4)));

#if __has_builtin(__builtin_amdgcn_exp2f)
#define EXP2(x) __builtin_amdgcn_exp2f(x)
#else
#define EXP2(x) exp2f(x)
#endif

__device__ __forceinline__ ushort f2bf(float f) {
    uint u = __builtin_bit_cast(uint, f);
    return (ushort)((u + 0x7FFFu + ((u >> 16) & 1u)) >> 16);
}
__device__ __forceinline__ float bf2f(ushort b) {
    return __builtin_bit_cast(float, ((uint)b) << 16);
}

// ---------------- Kernel 1 (fused): embed(conv+LN+pos, inline per head) + proj
// + fused q2 + woutT. Grid (256, 9):
//   y = h < 8 : block = 16 rows x head h. Stage conv_w+voxel, compute emb rows
//               in LDS (recomputed per head - trivial FLOPs, weights L2-hot),
//               then QK/V projections + q2 (v3 body). No emb global round-trip.
//   y = 8     : blocks 0..7 transpose wout -> woutT bf16; rest return.
// Replaces 3 dispatches (k_embed, k_proj, k_wt) with 1.
__global__ __launch_bounds__(256) void k_embproj(
    const float* __restrict__ voxel, const float* __restrict__ conv_w,
    const float* __restrict__ conv_b, const float* __restrict__ ln_g,
    const float* __restrict__ ln_b, const float* __restrict__ pos,
    const float* __restrict__ wqk, const float* __restrict__ bqk,
    const float* __restrict__ wv, const float* __restrict__ bvv,
    const float* __restrict__ wout,
    ushort* __restrict__ qk_bf,      // [H][4096][64]
    ushort* __restrict__ vT_bf,      // [H][64][4096]
    float* __restrict__ q2,          // [H][4096]
    ushort* __restrict__ woutT)      // [64][512]
{
    __shared__ float smem[64 * 65 + 16 * 64 + 16 * 64];  // wsm | vox | es
    float (*wsm)[65] = (float(*)[65])smem;
    float (*vox)[64] = (float(*)[64])(smem + 64 * 65);
    float (*es)[64]  = (float(*)[64])(smem + 64 * 65 + 16 * 64);
    const int t = threadIdx.x;

    if (blockIdx.y == 8) {           // ---- woutT role
        if (blockIdx.x >= 8) return;
        const int b = blockIdx.x;    // k-slab of 64
        for (int i = t; i < 4096; i += 256)
            wsm[i >> 6][i & 63] = wout[(b * 64 + (i >> 6)) * 64 + (i & 63)];
        __syncthreads();
        const int o = t >> 2, kb = (t & 3) * 16;
        #pragma unroll
        for (int j = 0; j < 16; j++)
            woutT[o * 512 + b * 64 + kb + j] = f2bf(wsm[kb + j][o]);
        return;
    }

    const int bx = blockIdx.x, h = blockIdx.y;
    const int n0 = bx * 16;
    const int d = bx >> 4, hh = bx & 15;   // 16 patches share (d,hh); ww=0..15
    const int e = t & 63, rg = t >> 6;

    for (int i = t; i < 4096; i += 256) wsm[i >> 6][i & 63] = conv_w[i];
    {
        const int pair = t >> 4;                 // i*4+j
        const int off4 = (t & 15) * 4;           // ww*4+k chunk
        const float4 v = *(const float4*)&voxel[(d * 4 + (pair >> 2)) * 4096 +
                                                (hh * 4 + (pair & 3)) * 64 + off4];
        *(float4*)&vox[pair][off4] = v;
    }
    __syncthreads();

    // ---- embed rows rg*4+rr (identical math/order to measured k_embed v3)
    {
        float acc[4];
        #pragma unroll
        for (int rr = 0; rr < 4; rr++) acc[rr] = conv_b[e];
        for (int m = 0; m < 64; m++) {
            const float wm = wsm[e][m];
            #pragma unroll
            for (int rr = 0; rr < 4; rr++)
                acc[rr] += vox[m >> 2][(rg * 4 + rr) * 4 + (m & 3)] * wm;
        }
        #pragma unroll
        for (int rr = 0; rr < 4; rr++) {
            const int row = rg * 4 + rr;
            float s1 = acc[rr], s2 = acc[rr] * acc[rr];
            #pragma unroll
            for (int off = 1; off < 64; off <<= 1) {
                s1 += __shfl_xor(s1, off);
                s2 += __shfl_xor(s2, off);
            }
            const float mu  = s1 * (1.0f / 64.0f);
            const float var = s2 * (1.0f / 64.0f) - mu * mu;
            es[row][e] = (acc[rr] - mu) * rsqrtf(var + 1e-5f) * ln_g[e] + ln_b[e] +
                         pos[(n0 + row) * 64 + e];
        }
    }
    __syncthreads();

    // ---- projections + q2 (v3 body)
    const int he = h * 64 + e;
    const float bq = bqk[he], bv = bvv[he];
    float aq[4] = {bq, bq, bq, bq};
    float av[4] = {bv, bv, bv, bv};

    for (int ep = 0; ep < 64; ep++) {
        const float wq  = wqk[ep * HE + he];
        const float wvv = wv[ep * HE + he];
        #pragma unroll
        for (int rr = 0; rr < 4; rr++) {
            const float x = es[rg * 4 + rr][ep];
            aq[rr] += x * wq;
            av[rr] += x * wvv;
        }
    }

    u16x4 vpk;
    #pragma unroll
    for (int rr = 0; rr < 4; rr++) {
        const int n = n0 + rg * 4 + rr;
        const ushort qb = f2bf(aq[rr]);
        qk_bf[((size_t)h * NPAT + n) * 64 + e] = qb;
        const float qf = bf2f(qb);
        float s = qf * qf;
        #pragma unroll
        for (int off = 1; off < 64; off <<= 1) s += __shfl_xor(s, off);
        if (e == 0) q2[h * NPAT + n] = s;
        vpk[rr] = f2bf(av[rr]);
    }
    *(u16x4*)&vT_bf[((size_t)h * 64 + e) * NPAT + n0 + rg * 4] = vpk;
}

// ---------------- Kernel 3: fused L2-distance attention, LDS-staged KV stream
// v2: depth-2 prefetch. 3 KV buffers; counted s_waitcnt vmcnt(1) (never 0 in
// the main loop) + raw s_barrier replaces the __syncthreads full drain, so each
// tile's staging flies ~2 iterations (~500cy) ahead of consumption (covers L2
// latency). q2 row staged to LDS once so the K-loop issues NO other vmem ops
// (keeps the vmcnt count exact). Buffer hazard: STAGE at iter it targets
// (it+2)%3 == (it-1)%3, whose reads retired before the top barrier of it.
__global__ __launch_bounds__(1024, 8) void k_attn(
    const ushort* __restrict__ qk,   // [H][N][64] bf16
    const ushort* __restrict__ vT,   // [H][64][N] bf16
    const float* __restrict__ q2,    // [H][N]
    const float* __restrict__ alpha, // [1]
    ushort* __restrict__ attn)       // [N][512] bf16
{
    const int bid = blockIdx.x;
    const int h  = bid & 7;
    const int bx = bid >> 3;
    const int tid = threadIdx.x;
    const int w  = tid >> 6;            // wave 0..15
    const int u  = w & 3;               // col-role (t-subtile for QK, c-tile for PV)
    const int rg = w >> 2;              // row group 0..3
    const int l  = tid & 63;
    const int lr = l & 15;
    const int lg = l >> 4;
    const float L2E = 1.4426950408889634f;
    const float ccl2e = alpha[0] * 0.125f * L2E;

    __shared__ ushort kv_lds[3][2][64 * 64]; // [buf][0=K,1=V] 48 KB
    __shared__ ushort p_lds[4][16 * 64];     // per-rg P tile, XOR-swizzled (8 KB)
    __shared__ float  zpart[4][4][16];       // z stripe-sums (1 KB)
    __shared__ float  q2s[4096];             // head's q2 row (16 KB)

    const ushort* qkh = qk + (size_t)h * NPAT * 64;
    const ushort* vTh = vT + (size_t)h * 64 * NPAT;
    const float*  q2h = q2 + h * NPAT;

    const int row0 = bx * 64 + rg * 16;

    bf16x8 aq0, aq1;
    {
        const ushort* qrow = qkh + (size_t)(row0 + lr) * 64 + 8 * lg;
        aq0 = *(const bf16x8*)(qrow);
        aq1 = *(const bf16x8*)(qrow + 32);
    }
    float nq2[4];
    #pragma unroll
    for (int r = 0; r < 4; r++) nq2[r] = q2h[row0 + 4 * lg + r];

    // stage q2 row into LDS (1024 thr x float4)
    *(float4*)&q2s[tid * 4] = *(const float4*)&q2h[tid * 4];

    const int w8   = w & 7;
    const int srow = w8 * 8 + (l >> 3);
    const int sch  = (l & 7) ^ (srow & 7);
    const ushort* ksrc0 = qkh + (size_t)srow * 64 + sch * 8;
    const ushort* vsrc0 = vTh + (size_t)srow * NPAT + sch * 8;
#define STAGE(bufi, it)                                                          \
    do {                                                                         \
        const ushort* _src = (w < 8) ? (ksrc0 + (size_t)(it) * 4096)             \
                                     : (vsrc0 + (size_t)(it) * 64);              \
        ushort* _dst = &kv_lds[bufi][w >> 3][w8 * 512];                          \
        __builtin_amdgcn_global_load_lds(                                        \
            (const __attribute__((address_space(1))) unsigned int*)_src,         \
            (__attribute__((address_space(3))) unsigned int*)_dst, 16, 0, 0);    \
    } while (0)

    f32x4 acc = (f32x4){0.f, 0.f, 0.f, 0.f};
    float zacc[4] = {0.f, 0.f, 0.f, 0.f};

    const int x7 = (lr & 7);
    char* prg = (char*)&p_lds[rg][0];

    STAGE(0, 0);
    STAGE(1, 1);
    __syncthreads();   // drain prologue stages + q2s writes; pipeline refills below

    int buf = 0;
    for (int it = 0; it < 64; ++it) {
        // wait own oldest stage (buf) done, keep deeper ones in flight; then
        // barrier so EVERYONE's buf-stage is visible.
        if (it == 63) { asm volatile("s_waitcnt vmcnt(0)" ::: "memory"); }
        else         { asm volatile("s_waitcnt vmcnt(1)" ::: "memory"); }
        __builtin_amdgcn_s_barrier();
        if (it + 2 < 64) {
            int b2 = buf + 2; if (b2 >= 3) b2 -= 3;
            STAGE(b2, it + 2);
        }
        const float k2c = q2s[it * 64 + u * 16 + lr];

        {
            const ushort* kb = &kv_lds[buf][0][0];
            const int krow = u * 16 + lr;
            bf16x8 bk0 = *(const bf16x8*)(kb + krow * 64 + ((lg ^ x7) << 3));
            bf16x8 bk1 = *(const bf16x8*)(kb + krow * 64 + (((lg + 4) ^ x7) << 3));
            f32x4 sc = (f32x4){0.f, 0.f, 0.f, 0.f};
            sc = __builtin_amdgcn_mfma_f32_16x16x32_bf16(aq0, bk0, sc, 0, 0, 0);
            sc = __builtin_amdgcn_mfma_f32_16x16x32_bf16(aq1, bk1, sc, 0, 0, 0);
            #pragma unroll
            for (int r = 0; r < 4; r++) {
                const float d = nq2[r] + k2c - 2.0f * sc[r];
                const float p = EXP2(ccl2e * EXP2(-L2E * d));
                zacc[r] += p;
                const int prow = 4 * lg + r, pcol = 16 * u + lr;
                const int byteoff = prow * 128 + ((pcol * 2) ^ ((prow & 7) << 4));
                *(ushort*)(prg + byteoff) = f2bf(p);
            }
        }
        asm volatile("s_waitcnt lgkmcnt(0)" ::: "memory");
        __builtin_amdgcn_s_barrier();

        {
            const ushort* vb = &kv_lds[buf][1][0];
            const int vrow = u * 16 + lr;
            bf16x8 bv0 = *(const bf16x8*)(vb + vrow * 64 + ((lg ^ x7) << 3));
            bf16x8 bv1 = *(const bf16x8*)(vb + vrow * 64 + (((lg + 4) ^ x7) << 3));
            char* rb = prg + lr * 128;
            const int xx = x7 << 4;
            bf16x8 pa0 = *(const bf16x8*)(rb + ((16 * lg) ^ xx));
            bf16x8 pa1 = *(const bf16x8*)(rb + ((64 + 16 * lg) ^ xx));
            acc = __builtin_amdgcn_mfma_f32_16x16x32_bf16(pa0, bv0, acc, 0, 0, 0);
            acc = __builtin_amdgcn_mfma_f32_16x16x32_bf16(pa1, bv1, acc, 0, 0, 0);
        }
        buf = (buf == 2) ? 0 : buf + 1;
    }
#undef STAGE

    #pragma unroll
    for (int r = 0; r < 4; r++) {
        float z = zacc[r];
        z += __shfl_xor(z, 1); z += __shfl_xor(z, 2);
        z += __shfl_xor(z, 4); z += __shfl_xor(z, 8);
        if (lr == 0) zpart[rg][u][4 * lg + r] = z;
    }
    __syncthreads();
    #pragma unroll
    for (int r = 0; r < 4; r++) {
        const int row = 4 * lg + r;
        const float zt = zpart[rg][0][row] + zpart[rg][1][row] +
                         zpart[rg][2][row] + zpart[rg][3][row];
        attn[(size_t)(row0 + row) * HE + h * 64 + u * 16 + lr] = f2bf(acc[r] / zt);
    }
}

// ---------------- Kernel 4 v3: out = attn_bf @ woutT^T + bout via MFMA
__global__ __launch_bounds__(256) void k_out(
    const ushort* __restrict__ attn,  // [4096][512] bf16
    const ushort* __restrict__ woutT, // [64][512] bf16
    const float* __restrict__ bout,   // [64]
    float* __restrict__ out)          // [4096][64]
{
    const int n0 = blockIdx.x * 8;
    const int t = threadIdx.x;
    const int w = t >> 6, l = t & 63, lr = l & 15, lg = l >> 4;
    __shared__ ushort sa[8][520];     // +8 pad

    for (int c = t; c < 512; c += 256) {
        const int row = c >> 6, c8 = c & 63;
        *(bf16x8*)&sa[row][c8 * 8] = *(const bf16x8*)&attn[(size_t)(n0 + row) * 512 + c8 * 8];
    }
    __syncthreads();

    f32x4 acc = (f32x4){0.f, 0.f, 0.f, 0.f};
    const ushort* bp = woutT + (size_t)(w * 16 + lr) * 512 + 8 * lg;
    #pragma unroll
    for (int kk = 0; kk < 16; kk++) {
        bf16x8 a = *(const bf16x8*)&sa[lr & 7][kk * 32 + 8 * lg];
        bf16x8 bb = *(const bf16x8*)(bp + kk * 32);
        acc = __builtin_amdgcn_mfma_f32_16x16x32_bf16(a, bb, acc, 0, 0, 0);
    }
    if (lg < 2) {
        const float bo = bout[w * 16 + lr];
        #pragma unroll
        for (int r = 0; r < 4; r++)
            out[(size_t)(n0 + 4 * lg + r) * 64 + w * 16 + lr] = acc[r] + bo;
    }
}

extern "C" void kernel_launch(void* const* d_in, const int* in_sizes, int n_in,
                              void* d_out, int out_size, void* d_ws, size_t ws_size,
                              hipStream_t stream) {
    (void)in_sizes; (void)n_in; (void)out_size; (void)ws_size;
    const float* voxel  = (const float*)d_in[0];
    const float* conv_w = (const float*)d_in[1];
    const float* conv_b = (const float*)d_in[2];
    const float* ln_g   = (const float*)d_in[3];
    const float* ln_b   = (const float*)d_in[4];
    const float* pos    = (const float*)d_in[5];
    const float* wqk    = (const float*)d_in[6];
    const float* bqk    = (const float*)d_in[7];
    const float* wv     = (const float*)d_in[8];
    const float* bvv    = (const float*)d_in[9];
    const float* alpha  = (const float*)d_in[10];
    const float* wout   = (const float*)d_in[11];
    const float* bout   = (const float*)d_in[12];
    float* out = (float*)d_out;

    char* ws = (char*)d_ws;
    ushort* qk_bf   = (ushort*)(ws + (1u << 20));                      // 4 MB
    ushort* vT_bf   = (ushort*)(ws + 5u * (1u << 20));                 // 4 MB
    float*  q2      = (float*) (ws + 9u * (1u << 20));                 // 128 KB
    ushort* attn_bf = (ushort*)(ws + 9u * (1u << 20) + (128u << 10));  // 4 MB
    ushort* woutT   = (ushort*)(ws + 13u * (1u << 20) + (128u << 10)); // 64 KB

    k_embproj<<<dim3(NPAT / 16, NH + 1), 256, 0, stream>>>(
        voxel, conv_w, conv_b, ln_g, ln_b, pos, wqk, bqk, wv, bvv, wout,
        qk_bf, vT_bf, q2, woutT);
    k_attn<<<NPAT / 64 * NH, 1024, 0, stream>>>(qk_bf, vT_bf, q2, alpha, attn_bf);
    k_out<<<NPAT / 8, 256, 0, stream>>>(attn_bf, woutT, bout, out);
}